// Round 8
// baseline (29.834 us; speedup 1.0000x reference)
//
#include <hip/hip_runtime.h>
#include <math.h>

#define BB 2
#define C_IN 32
#define HH 64
#define WW 64
#define J (HH*WW)        // 4096
#define HID 64
#define C_OUT 32
#define S 256
#define TN 128           // table knots per (b,h)
#define JT 16            // j's per eval block

// gelu(x) ~= x * sigmoid(A*x + B*x^3)  (tanh-form gelu, exp2 domain)
#define GELU_A 2.3022043f
#define GELU_B 0.10294306f

// ---------- kernel A: T[b,h,n] = sum_s gelu(c_n + u[b,s,h]) ----------
// grid 512 = (b, h, knot-quarter). u[b,:,h] recomputed in-block.
__global__ __launch_bounds__(256) void k_table(
    const float* __restrict__ v, const int* __restrict__ indices,
    const float* __restrict__ W1, const float* __restrict__ b1,
    float* __restrict__ T)
{
    __shared__ float us[8 * 33];         // u[b,:,h] in 8 padded s-groups of 32
    int tid = threadIdx.x;
    int blk = blockIdx.x;                // 0..511
    int b   = blk >> 8;                  // 0..1
    int rem = blk & 255;
    int h   = rem >> 2;                  // 0..63
    int nq  = rem & 3;                   // knot quarter

    float w0 = W1[h], w1 = W1[HID + h];

    // --- recompute u[b,s,h] for s = tid ---
    {
        int s   = tid;
        int idx = indices[s];
        float sx = (float)(idx & (WW - 1)) * (1.0f / (WW - 1));
        float sy = (float)(idx >> 6)       * (1.0f / (HH - 1));
        float acc = b1[h] - sx * w0 - sy * w1;
        const float* vb = v + (size_t)b * C_IN * J + idx;
        #pragma unroll
        for (int c = 0; c < C_IN; ++c) {
            acc = __builtin_fmaf(vb[c * J], W1[(2 + c) * HID + h], acc);
        }
        us[(s >> 5) * 33 + (s & 31)] = acc;
    }
    __syncthreads();

    // --- knot sum: n = nq*32 + tid>>3, 8 s-groups in parallel ---
    float c0 = fminf(w0, 0.0f) + fminf(w1, 0.0f);
    float c1 = fmaxf(w0, 0.0f) + fmaxf(w1, 0.0f);
    float dc = fmaxf(c1 - c0, 1e-6f) * (1.0f / (TN - 1));
    int n  = nq * 32 + (tid >> 3);
    int sg = tid & 7;                    // s-group
    float cn = c0 + (float)n * dc;

    const float* usp = &us[sg * 33];
    float acc = 0.0f;
    #pragma unroll 4
    for (int s = 0; s < 32; ++s) {
        float x = cn + usp[s];
        float p = __builtin_fmaf(-GELU_B, x * x, -GELU_A);
        float e = __builtin_amdgcn_exp2f(p * x);
        acc = __builtin_fmaf(x, __builtin_amdgcn_rcpf(e + 1.0f), acc);
    }
    acc += __shfl_xor(acc, 1);           // combine 8 s-groups
    acc += __shfl_xor(acc, 2);
    acc += __shfl_xor(acc, 4);
    if (sg == 0)
        T[((size_t)b * HID + h) * TN + n] = acc;
}

// ---------- kernel B: interp + W2 epilogue, grid 512 = (b, j-tile of 16) ----------
__global__ __launch_bounds__(256) void k_eval(
    const float* __restrict__ T, const float* __restrict__ W1,
    const float* __restrict__ W2, const float* __restrict__ b2,
    float* __restrict__ out)
{
    __shared__ float Tl[HID][TN + 4];    // row stride 132 floats, 16B-aligned
    __shared__ float G[JT][HID + 1];
    int tid = threadIdx.x;
    int blk = blockIdx.x;                // 0..511
    int b   = blk >> 8;
    int j0  = (blk & 255) * JT;

    // stage this batch's table (32 KB) into LDS, float4 loads
    const float4* Tb4 = (const float4*)(T + (size_t)b * HID * TN);
    #pragma unroll
    for (int k = tid; k < HID * TN / 4; k += 256) {   // 8 iters
        float4 vv = Tb4[k];
        int h = k >> 5;                  // 32 float4 per table row
        int n = (k & 31) * 4;
        *(float4*)&Tl[h][n] = vv;
    }
    __syncthreads();

    // interp: thread -> (j = j0 + tid&15, h = (tid>>4) + 16k)
    int jl = tid & 15;
    int j  = j0 + jl;
    float xj = (float)(j & (WW - 1)) * (1.0f / (WW - 1));
    float yj = (float)(j >> 6)       * (1.0f / (HH - 1));
    #pragma unroll
    for (int k = 0; k < 4; ++k) {
        int h = (tid >> 4) + k * 16;
        float w0 = W1[h], w1 = W1[HID + h];
        float c0 = fminf(w0, 0.0f) + fminf(w1, 0.0f);
        float c1 = fmaxf(w0, 0.0f) + fmaxf(w1, 0.0f);
        float inv = (float)(TN - 1) / fmaxf(c1 - c0, 1e-6f);
        float t  = (xj * w0 + yj * w1 - c0) * inv;
        int i = (int)t;
        i = max(0, min(TN - 2, i));
        float f = t - (float)i;
        float t0 = Tl[h][i], t1 = Tl[h][i + 1];
        G[jl][h] = __builtin_fmaf(f, t1 - t0, t0);
    }
    __syncthreads();

    // epilogue: 2 outputs/thread; lanes vary jj -> coalesced-ish stores
    int jj = tid & 15;
    int cb = tid >> 4;                   // 0..15
    #pragma unroll
    for (int qq = 0; qq < 2; ++qq) {
        int co = cb + 16 * qq;
        float sum = 0.0f;
        #pragma unroll
        for (int h = 0; h < HID; ++h)
            sum = __builtin_fmaf(G[jj][h], W2[h * C_OUT + co], sum);
        out[(size_t)b * C_OUT * J + (size_t)co * J + j0 + jj] = sum * (1.0f / S) + b2[co];
    }
}

extern "C" void kernel_launch(void* const* d_in, const int* in_sizes, int n_in,
                              void* d_out, int out_size, void* d_ws, size_t ws_size,
                              hipStream_t stream) {
    const float* v       = (const float*)d_in[0];
    const int*   indices = (const int*)  d_in[1];
    const float* W1      = (const float*)d_in[2];
    const float* b1      = (const float*)d_in[3];
    const float* W2      = (const float*)d_in[4];
    const float* b2      = (const float*)d_in[5];
    float* out = (float*)d_out;
    float* T   = (float*)d_ws;           // B*HID*TN*4 = 64 KB

    hipLaunchKernelGGL(k_table, dim3(512), dim3(256), 0, stream,
                       v, indices, W1, b1, T);
    hipLaunchKernelGGL(k_eval,  dim3(512), dim3(256), 0, stream,
                       T, W1, W2, b2, out);
}

// Round 9
// 24.102 us; speedup vs baseline: 1.2378x; 1.2378x over previous
//
#include <hip/hip_runtime.h>
#include <math.h>

#define BB 2
#define C_IN 32
#define HH 64
#define WW 64
#define J (HH*WW)        // 4096
#define HID 64
#define C_OUT 32
#define S 256
#define TN 128           // table knots per (b,h)
#define JT 32            // j's per eval block

// gelu(x) ~= x * sigmoid(A*x + B*x^3)  (tanh-form gelu, exp2 domain)
#define GELU_A 2.3022043f
#define GELU_B 0.10294306f

// ---------- kernel 0: ut[b,h,s] = b1 - sx*w0 - sy*w1 + vp[b,idx_s]@W1[2:] ----------
// one block per (b,s): idx is wave-uniform -> scalar-broadcast v loads.
__global__ __launch_bounds__(64) void k_prep(
    const float* __restrict__ v, const int* __restrict__ indices,
    const float* __restrict__ W1, const float* __restrict__ b1,
    float* __restrict__ ut)
{
    int bs  = blockIdx.x;            // 0..B*S-1
    int b   = bs >> 8;
    int s   = bs & 255;
    int h   = threadIdx.x;           // 0..63
    int idx = indices[s];
    float sx = (float)(idx & (WW - 1)) * (1.0f / (WW - 1));
    float sy = (float)(idx >> 6)       * (1.0f / (HH - 1));
    float acc = b1[h] - sx * W1[h] - sy * W1[HID + h];
    const float* vb = v + (size_t)b * C_IN * J + idx;
    #pragma unroll
    for (int c = 0; c < C_IN; ++c) {
        acc = __builtin_fmaf(vb[c * J], W1[(2 + c) * HID + h], acc);
    }
    ut[((size_t)b * HID + h) * S + s] = acc;   // transposed: contiguous per (b,h)
}

// ---------- kernel A: T[b,h,n] = sum_s gelu(c_n + ut[b,h,s]) ----------
// 1024 blocks = (b, h, 16-knot group); 16 threads/knot x 16 s each.
__global__ __launch_bounds__(256) void k_table(
    const float* __restrict__ ut, const float* __restrict__ W1,
    float* __restrict__ T)
{
    __shared__ float us[16 * 20];        // 16 padded s-groups of 16 (stride 20: float4-aligned)
    int tid = threadIdx.x;
    int blk = blockIdx.x;                // 0..1023
    int b   = blk >> 9;                  // 0..1
    int h   = (blk >> 3) & 63;
    int ng  = blk & 7;                   // knot group (16 knots)

    // coalesced row load: 256 floats = 64 float4
    if (tid < 64) {
        const float4* row4 = (const float4*)(ut + ((size_t)b * HID + h) * S);
        float4 vv = row4[tid];
        *(float4*)&us[(tid >> 2) * 20 + (tid & 3) * 4] = vv;
    }
    __syncthreads();

    float w0 = W1[h], w1 = W1[HID + h];
    float c0 = fminf(w0, 0.0f) + fminf(w1, 0.0f);
    float c1 = fmaxf(w0, 0.0f) + fmaxf(w1, 0.0f);
    float dc = fmaxf(c1 - c0, 1e-6f) * (1.0f / (TN - 1));
    int n  = ng * 16 + (tid >> 4);       // knot index
    int sg = tid & 15;                   // s-group
    float cn = c0 + (float)n * dc;

    const float* usp = &us[sg * 20];
    float acc = 0.0f;
    #pragma unroll
    for (int s = 0; s < 16; ++s) {
        float x = cn + usp[s];
        float p = __builtin_fmaf(-GELU_B, x * x, -GELU_A);
        float e = __builtin_amdgcn_exp2f(p * x);
        acc = __builtin_fmaf(x, __builtin_amdgcn_rcpf(e + 1.0f), acc);
    }
    acc += __shfl_xor(acc, 1);           // combine 16 s-groups (lane bits 0..3)
    acc += __shfl_xor(acc, 2);
    acc += __shfl_xor(acc, 4);
    acc += __shfl_xor(acc, 8);
    if (sg == 0)
        T[((size_t)b * HID + h) * TN + n] = acc;
}

// ---------- kernel B: interp + W2 epilogue (unchanged from R7) ----------
__global__ __launch_bounds__(256) void k_eval(
    const float* __restrict__ T, const float* __restrict__ W1,
    const float* __restrict__ W2, const float* __restrict__ b2,
    float* __restrict__ out)
{
    __shared__ float Tl[HID][TN + 4];    // row stride 132 floats, 16B-aligned
    __shared__ float G[JT][HID + 1];
    int tid = threadIdx.x;
    int blk = blockIdx.x;                // 0..255
    int b   = blk >> 7;
    int j0  = (blk & 127) * JT;

    const float4* Tb4 = (const float4*)(T + (size_t)b * HID * TN);
    #pragma unroll
    for (int k = tid; k < HID * TN / 4; k += 256) {   // 8 iters
        float4 vv = Tb4[k];
        int h = k >> 5;                  // 32 float4 per table row
        int n = (k & 31) * 4;
        *(float4*)&Tl[h][n] = vv;
    }
    __syncthreads();

    int jl = tid & 31;
    int j  = j0 + jl;
    float xj = (float)(j & (WW - 1)) * (1.0f / (WW - 1));
    float yj = (float)(j >> 6)       * (1.0f / (HH - 1));
    #pragma unroll
    for (int k = 0; k < 8; ++k) {
        int h = (tid >> 5) + k * 8;
        float w0 = W1[h], w1 = W1[HID + h];
        float c0 = fminf(w0, 0.0f) + fminf(w1, 0.0f);
        float c1 = fmaxf(w0, 0.0f) + fmaxf(w1, 0.0f);
        float inv = (float)(TN - 1) / fmaxf(c1 - c0, 1e-6f);
        float t  = (xj * w0 + yj * w1 - c0) * inv;
        int i = (int)t;
        i = max(0, min(TN - 2, i));
        float f = t - (float)i;
        float t0 = Tl[h][i], t1 = Tl[h][i + 1];
        G[jl][h] = __builtin_fmaf(f, t1 - t0, t0);
    }
    __syncthreads();

    int jj = tid & 31;
    int cb = tid >> 5;                   // 0..7
    #pragma unroll
    for (int qq = 0; qq < 4; ++qq) {
        int co = cb + 8 * qq;
        float sum = 0.0f;
        #pragma unroll
        for (int h = 0; h < HID; ++h)
            sum = __builtin_fmaf(G[jj][h], W2[h * C_OUT + co], sum);
        out[(size_t)b * C_OUT * J + (size_t)co * J + j0 + jj] = sum * (1.0f / S) + b2[co];
    }
}

extern "C" void kernel_launch(void* const* d_in, const int* in_sizes, int n_in,
                              void* d_out, int out_size, void* d_ws, size_t ws_size,
                              hipStream_t stream) {
    const float* v       = (const float*)d_in[0];
    const int*   indices = (const int*)  d_in[1];
    const float* W1      = (const float*)d_in[2];
    const float* b1      = (const float*)d_in[3];
    const float* W2      = (const float*)d_in[4];
    const float* b2      = (const float*)d_in[5];
    float* out = (float*)d_out;
    float* ut  = (float*)d_ws;                         // B*HID*S*4  = 128 KB
    float* T   = (float*)d_ws + (size_t)BB * HID * S;  // B*HID*TN*4 =  64 KB

    hipLaunchKernelGGL(k_prep,  dim3(BB * S), dim3(64),  0, stream,
                       v, indices, W1, b1, ut);
    hipLaunchKernelGGL(k_table, dim3(1024),   dim3(256), 0, stream,
                       ut, W1, T);
    hipLaunchKernelGGL(k_eval,  dim3(256),    dim3(256), 0, stream,
                       T, W1, W2, b2, out);
}